// Round 2
// baseline (1028.630 us; speedup 1.0000x reference)
//
#include <hip/hip_runtime.h>

#define N_NODES 16384
#define N_EDGES 8192
#define D_FEAT  64

typedef __attribute__((ext_vector_type(8))) short short8;
typedef __attribute__((ext_vector_type(4))) float floatx4;

__device__ __forceinline__ unsigned short f2bf(float f) {
    unsigned int u = __float_as_uint(f);
    return (unsigned short)((u + 0x7fffu + ((u >> 16) & 1u)) >> 16);
}

// Packed fp32->bf16 (RNE), 2 elements per instruction. lo -> D[15:0], hi -> D[31:16].
__device__ __forceinline__ unsigned int cvtpk(float lo, float hi) {
    unsigned int r;
    asm("v_cvt_pk_bf16_f32 %0, %1, %2" : "=v"(r) : "v"(lo), "v"(hi));
    return r;
}

// Swizzled LDS dword index: row-stride 32 dwords (64 bf16), XOR on group-of-4
// keeps ds_read_b128 contiguity while spreading rows across banks.
__device__ __forceinline__ int sw(int row, int g) {
    return row * 32 + (g ^ (((row >> 3) & 7) * 4));
}

// Pass 1: dv[n] = row-sum of fp32 H; Hbf = bf16(H); Xs = dv[n]*F (fp32).
// H loads are non-temporal: read-once stream, keep L3 free for the Hbf writes.
__global__ __launch_bounds__(256) void dvscale_kernel(const float* __restrict__ H,
                                                      const float* __restrict__ F,
                                                      float* __restrict__ dv,
                                                      unsigned short* __restrict__ Hbf,
                                                      float* __restrict__ Xs) {
    const int wave = threadIdx.x >> 6;
    const int lane = threadIdx.x & 63;
    const int n = blockIdx.x * 4 + wave;
    const floatx4* row = (const floatx4*)(H + (size_t)n * N_EDGES);
    unsigned short* hrow = Hbf + (size_t)n * N_EDGES;
    float s = 0.f;
#pragma unroll
    for (int j = 0; j < 16; ++j) {
        floatx4 v0 = __builtin_nontemporal_load(&row[2 * lane + 128 * j]);
        floatx4 v1 = __builtin_nontemporal_load(&row[2 * lane + 128 * j + 1]);
        s += v0[0] + v0[1] + v0[2] + v0[3];
        s += v1[0] + v1[1] + v1[2] + v1[3];
        uint4 pk;
        pk.x = cvtpk(v0[0], v0[1]);
        pk.y = cvtpk(v0[2], v0[3]);
        pk.z = cvtpk(v1[0], v1[1]);
        pk.w = cvtpk(v1[2], v1[3]);
        *(uint4*)(hrow + 8 * (lane + 64 * j)) = pk;
    }
#pragma unroll
    for (int off = 32; off > 0; off >>= 1) s += __shfl_down(s, off, 64);
    s = __shfl(s, 0, 64);
    if (lane == 0) dv[n] = s;
    Xs[(size_t)n * D_FEAT + lane] = F[(size_t)n * D_FEAT + lane] * s;
}

// Transpose Xs[16384][64] fp32 -> XsT[64][16384] bf16.
__global__ __launch_bounds__(256) void xst_kernel(const float* __restrict__ Xs,
                                                  unsigned short* __restrict__ XsT) {
    __shared__ float tile[64][65];
    const int n0 = blockIdx.x * 64;
    const int t = threadIdx.x;
    const int r = t >> 4, c4 = t & 15;
#pragma unroll
    for (int li = 0; li < 4; ++li) {
        const int rr = r + 16 * li;
        float4 v = *(const float4*)(Xs + (size_t)(n0 + rr) * 64 + c4 * 4);
        tile[rr][c4 * 4 + 0] = v.x; tile[rr][c4 * 4 + 1] = v.y;
        tile[rr][c4 * 4 + 2] = v.z; tile[rr][c4 * 4 + 3] = v.w;
    }
    __syncthreads();
#pragma unroll
    for (int li = 0; li < 4; ++li) {
        const int d = r + 16 * li;
        unsigned long long pk = (unsigned long long)f2bf(tile[c4 * 4 + 0][d])
                              | ((unsigned long long)f2bf(tile[c4 * 4 + 1][d]) << 16)
                              | ((unsigned long long)f2bf(tile[c4 * 4 + 2][d]) << 32)
                              | ((unsigned long long)f2bf(tile[c4 * 4 + 3][d]) << 48);
        *(unsigned long long*)(XsT + (size_t)d * N_NODES + n0 + c4 * 4) = pk;
    }
}

// GEMM1: YaccT[d][e] += sum_n H[n][e]*Xs[n][d]  (K=nodes, split 16x), de fused.
// Grid 1024 = 64 e-tiles(128) x 16 k-splits(1024).
__global__ __launch_bounds__(256) void gemm1_kernel(const unsigned short* __restrict__ Hbf,
                                                    const unsigned short* __restrict__ XsT,
                                                    float* __restrict__ YaccT,
                                                    float* __restrict__ de) {
    __shared__ unsigned int A32[128 * 32];  // [e][k-pair] swizzled
    __shared__ unsigned int B32[64 * 32];   // [d][k-pair] swizzled
    const int t = threadIdx.x;
    const int w = t >> 6;
    const int lane = t & 63;
    const int e0 = (blockIdx.x & 63) * 128;
    const int k0base = (blockIdx.x >> 6) * 1024;

    const int seg = t & 15;   // A: e-seg of 8
    const int p = t >> 4;     // A: node-pair 0..15 (+16)
    const int bd = t >> 3;    // B: d-row 0..31 (+32)
    const int bseg = t & 7;   // B: k-seg of 8

    floatx4 acc[2][4];
#pragma unroll
    for (int i = 0; i < 2; ++i)
#pragma unroll
        for (int j = 0; j < 4; ++j) acc[i][j] = (floatx4){0.f, 0.f, 0.f, 0.f};
    float dea[8] = {0.f, 0.f, 0.f, 0.f, 0.f, 0.f, 0.f, 0.f};

    for (int it = 0; it < 16; ++it) {
        const int k0 = k0base + it * 64;
        __syncthreads();
#pragma unroll
        for (int pp = 0; pp < 2; ++pp) {
            const int pr = p + 16 * pp;
            const unsigned short* src = Hbf + (size_t)(k0 + 2 * pr) * N_EDGES + e0 + seg * 8;
            short8 r0 = *(const short8*)src;
            short8 r1 = *(const short8*)(src + N_EDGES);
#pragma unroll
            for (int j = 0; j < 8; ++j) {
                unsigned int lo = (unsigned short)r0[j];
                unsigned int hi = (unsigned short)r1[j];
                unsigned int pk = lo | (hi << 16);
                const int e = seg * 8 + j;
                A32[sw(e, pr & ~3) + (pr & 3)] = pk;
                dea[j] += __uint_as_float(pk << 16) + __uint_as_float(pk & 0xffff0000u);
            }
        }
#pragma unroll
        for (int bb = 0; bb < 2; ++bb) {
            const int d = bd + 32 * bb;
            uint4 v = *(const uint4*)(XsT + (size_t)d * N_NODES + k0 + bseg * 8);
            *(uint4*)&B32[sw(d, bseg * 4)] = v;
        }
        __syncthreads();
#pragma unroll
        for (int s = 0; s < 2; ++s) {
            const int g = s * 16 + (lane >> 4) * 4;
            short8 af[2];
#pragma unroll
            for (int i = 0; i < 2; ++i) {
                const int row = 32 * w + 16 * i + (lane & 15);
                af[i] = *(short8*)&A32[sw(row, g)];
            }
#pragma unroll
            for (int j = 0; j < 4; ++j) {
                const int row = 16 * j + (lane & 15);
                short8 bf = *(short8*)&B32[sw(row, g)];
#pragma unroll
                for (int i = 0; i < 2; ++i)
                    acc[i][j] = __builtin_amdgcn_mfma_f32_16x16x32_bf16(af[i], bf, acc[i][j], 0, 0, 0);
            }
        }
    }

#pragma unroll
    for (int i = 0; i < 2; ++i)
#pragma unroll
        for (int j = 0; j < 4; ++j)
#pragma unroll
            for (int r = 0; r < 4; ++r) {
                const int e = e0 + 32 * w + 16 * i + (lane >> 4) * 4 + r;
                const int d = 16 * j + (lane & 15);
                atomicAdd(&YaccT[(size_t)d * N_EDGES + e], acc[i][j][r]);
            }
#pragma unroll
    for (int j = 0; j < 8; ++j) atomicAdd(&de[e0 + seg * 8 + j], dea[j]);
}

// scaley: Yt[d][e] = bf16(YaccT[d][e] * de[e]).  Grid 512.
__global__ __launch_bounds__(256) void scaley_kernel(const float* __restrict__ YaccT,
                                                     const float* __restrict__ de,
                                                     unsigned short* __restrict__ Yt) {
    const int idx = blockIdx.x * 256 + threadIdx.x;  // float4 idx over 64*8192/4
    const int d = idx >> 11;
    const int e4 = idx & 2047;
    float4 y = ((const float4*)YaccT)[idx];
    float4 sc = ((const float4*)de)[e4];
    unsigned long long pk = (unsigned long long)f2bf(y.x * sc.x)
                          | ((unsigned long long)f2bf(y.y * sc.y) << 16)
                          | ((unsigned long long)f2bf(y.z * sc.z) << 32)
                          | ((unsigned long long)f2bf(y.w * sc.w) << 48);
    *(unsigned long long*)(Yt + (size_t)d * N_EDGES + e4 * 4) = pk;
    (void)d;
}

// GEMM2: out[n][d] = dv[n] * sum_e Hbf[n][e]*Yt[d][e].  No split-K.
// Grid 256 = 256 m-tiles of 64 rows; K=8192 in BK=64 steps, double-buffered
// LDS with register staging (loads for it+2 stay in flight across the barrier).
__global__ __launch_bounds__(256) void gemm2_kernel(const unsigned short* __restrict__ Hbf,
                                                    const unsigned short* __restrict__ Yt,
                                                    const float* __restrict__ dv,
                                                    float* __restrict__ out) {
    __shared__ unsigned int A32[2][64 * 32];  // [buf][n-row][k-pair] swizzled, 8 KiB each
    __shared__ unsigned int B32[2][64 * 32];  // [buf][d-row][k-pair] swizzled
    const int t = threadIdx.x;
    const int w = t >> 6;
    const int lane = t & 63;
    const int m0 = blockIdx.x * 64;

    const int arow = t >> 3;  // 0..31 (+32)
    const int aseg = t & 7;   // k-seg of 8 bf16 (16B)

    const int l15 = lane & 15;
    const int l4 = lane >> 4;

    floatx4 acc[4];
#pragma unroll
    for (int j = 0; j < 4; ++j) acc[j] = (floatx4){0.f, 0.f, 0.f, 0.f};

    uint4 ra0, ra1, rb0, rb1;

    const unsigned short* aptr0 = Hbf + (size_t)(m0 + arow) * N_EDGES + aseg * 8;
    const unsigned short* aptr1 = Hbf + (size_t)(m0 + arow + 32) * N_EDGES + aseg * 8;
    const unsigned short* bptr0 = Yt + (size_t)arow * N_EDGES + aseg * 8;
    const unsigned short* bptr1 = Yt + (size_t)(arow + 32) * N_EDGES + aseg * 8;

#define G2_LOAD(k0)                                     \
    do {                                                \
        ra0 = *(const uint4*)(aptr0 + (k0));            \
        ra1 = *(const uint4*)(aptr1 + (k0));            \
        rb0 = *(const uint4*)(bptr0 + (k0));            \
        rb1 = *(const uint4*)(bptr1 + (k0));            \
    } while (0)

#define G2_WRITE(buf)                                   \
    do {                                                \
        *(uint4*)&A32[buf][sw(arow, aseg * 4)] = ra0;   \
        *(uint4*)&A32[buf][sw(arow + 32, aseg * 4)] = ra1; \
        *(uint4*)&B32[buf][sw(arow, aseg * 4)] = rb0;   \
        *(uint4*)&B32[buf][sw(arow + 32, aseg * 4)] = rb1; \
    } while (0)

    G2_LOAD(0);
    G2_WRITE(0);
    G2_LOAD(64);
    __syncthreads();

    int cur = 0;
    for (int it = 0; it < 128; ++it) {
        if (it < 127) G2_WRITE(cur ^ 1);              // data for it+1 (vmcnt waits on its loads)
        if (it < 126) G2_LOAD((it + 2) * 64);         // stays in flight across the barrier
#pragma unroll
        for (int s = 0; s < 2; ++s) {
            const int g = s * 16 + l4 * 4;
            short8 af = *(short8*)&A32[cur][sw(16 * w + l15, g)];
#pragma unroll
            for (int j = 0; j < 4; ++j) {
                short8 bfv = *(short8*)&B32[cur][sw(16 * j + l15, g)];
                acc[j] = __builtin_amdgcn_mfma_f32_16x16x32_bf16(af, bfv, acc[j], 0, 0, 0);
            }
        }
        __syncthreads();
        cur ^= 1;
    }

    float dvv[4];
#pragma unroll
    for (int r = 0; r < 4; ++r) dvv[r] = dv[m0 + 16 * w + l4 * 4 + r];
#pragma unroll
    for (int j = 0; j < 4; ++j)
#pragma unroll
        for (int r = 0; r < 4; ++r) {
            const int n = m0 + 16 * w + l4 * 4 + r;
            const int d = 16 * j + l15;
            out[(size_t)n * D_FEAT + d] = acc[j][r] * dvv[r];
        }
#undef G2_LOAD
#undef G2_WRITE
}

extern "C" void kernel_launch(void* const* d_in, const int* in_sizes, int n_in,
                              void* d_out, int out_size, void* d_ws, size_t ws_size,
                              hipStream_t stream) {
    const float* H = (const float*)d_in[0];
    const float* F = (const float*)d_in[1];
    float* out = (float*)d_out;
    char* base = (char*)d_ws;

    float* dv = (float*)base;                                   // 64 KiB
    float* de = (float*)(base + 65536);                         // 32 KiB
    float* Xs = (float*)(base + 98304);                         // 4 MiB
    float* YaccT = (float*)(base + 98304 + 4194304);            // 2 MiB
    // (hole where OutAcc used to live — layout kept stable)
    unsigned short* XsT = (unsigned short*)(base + 98304 + 4194304 + 2097152 + 4194304);  // 2 MiB
    unsigned short* Yt = XsT + (size_t)64 * N_NODES;            // 1 MiB
    unsigned short* Hbf = (unsigned short*)((char*)Yt + 1048576);  // 256 MiB

    (void)hipMemsetAsync(de, 0, N_EDGES * sizeof(float), stream);
    (void)hipMemsetAsync(YaccT, 0, (size_t)64 * N_EDGES * sizeof(float), stream);

    dvscale_kernel<<<N_NODES / 4, 256, 0, stream>>>(H, F, dv, Hbf, Xs);
    xst_kernel<<<N_NODES / 64, 256, 0, stream>>>(Xs, XsT);
    gemm1_kernel<<<1024, 256, 0, stream>>>(Hbf, XsT, YaccT, de);
    scaley_kernel<<<512, 256, 0, stream>>>(YaccT, de, Yt);
    gemm2_kernel<<<256, 256, 0, stream>>>(Hbf, Yt, dv, out);
}